// Round 1
// 250.182 us; speedup vs baseline: 1.2581x; 1.2581x over previous
//
#include <hip/hip_runtime.h>

typedef unsigned short u16;
typedef unsigned int u32;
typedef __attribute__((ext_vector_type(8))) short short8;
typedef __attribute__((ext_vector_type(4))) float f32x4;

#define DEV static __device__ __forceinline__

// ---- bf16 helpers ----
DEV u16 f2bf(float f) {               // RNE, manual (for scalar stores)
  u32 u = __builtin_bit_cast(u32, f);
  u += 0x7FFFu + ((u >> 16) & 1u);
  return (u16)(u >> 16);
}
DEV u32 cvtpk(float a, float b) {     // {lo=bf16(a), hi=bf16(b)}, HW RNE, 1 instr
  u32 d;
  asm("v_cvt_pk_bf16_f32 %0, %1, %2" : "=v"(d) : "v"(a), "v"(b));
  return d;
}
DEV short8 ld8(const u16* p) {        // 16B bf16 fragment load (global or LDS)
  uint4 v = *reinterpret_cast<const uint4*>(p);
  return __builtin_bit_cast(short8, v);
}

// Problem constants
#define BB 16
#define CC 256
#define DD 64
#define NN 4096

// ============================================================================
// Kernel P: one-time f32 -> bf16 weight conversion (unchanged).
// ============================================================================
__global__ __launch_bounds__(256) void prep_kernel(
    const float* __restrict__ wq, const float* __restrict__ wk,
    const float* __restrict__ wv, const float* __restrict__ wo,
    u16* __restrict__ wqb, u16* __restrict__ wkb,
    u16* __restrict__ wvb, u16* __restrict__ wob)
{
  int i = blockIdx.x * 256 + threadIdx.x;   // 64 blocks x 256 = 16384
  wqb[i] = f2bf(wq[i]);
  wkb[i] = f2bf(wk[i]);
  wvb[i] = f2bf(wv[i]);
  wob[i] = f2bf(wo[i]);
}

// ============================================================================
// Kernel A: QKV projection.
// Rewritten: (1) staging = register 4n x 8c micro-transpose + cvt_pk +
// swizzled ds_write_b128 (was: 64 scalar u16 writes/thread, 16-way conflicts);
// (2) wave w owns output tiles nt = {3w,3w+1,3w+2} -> 24 global weight-frag
// loads/thread (was 96, L1-thrashing); (3) V epilogue staged [ch][n] in LDS
// (Xs reuse) -> coalesced uint4 global writes (was 2B scatter at stride NN).
// Xs swizzle: 16B slot index ^= (row & 7)  -> conflict-free min-phase b128.
// ============================================================================
__global__ __launch_bounds__(256, 4) void qkv_kernel(
    const float* __restrict__ xg, const float* __restrict__ pos_e,
    const u16* __restrict__ wqb, const u16* __restrict__ wkb,
    const u16* __restrict__ wvb,
    const float* __restrict__ bq, const float* __restrict__ bk,
    const float* __restrict__ bv,
    u16* __restrict__ Qb, u16* __restrict__ Kb, u16* __restrict__ Vt)
{
  const int nc = blockIdx.x, b = blockIdx.y, tid = threadIdx.x;
  const int n0 = nc * 64;
  __shared__ u16 Xs[64 * 256];   // [n][c] bf16, swizzled; 32 KiB

  // ---- stage x[b, :, n0:n0+64] transposed via register micro-transpose ----
  {
    const int ng = tid & 15;          // n rows ng*4 .. ng*4+3
    const int ch0 = tid >> 4;
#pragma unroll
    for (int it = 0; it < 2; ++it) {
      const int c0 = (ch0 + 16 * it) * 8;     // c chunk of 8
      f32x4 xv[8];
#pragma unroll
      for (int j = 0; j < 8; ++j)
        xv[j] = *reinterpret_cast<const f32x4*>(
            xg + ((size_t)(b * CC + c0 + j)) * NN + n0 + ng * 4);
#pragma unroll
      for (int i = 0; i < 4; ++i) {
        const int n = ng * 4 + i;
        uint4 o;
        o.x = cvtpk(xv[0][i], xv[1][i]);
        o.y = cvtpk(xv[2][i], xv[3][i]);
        o.z = cvtpk(xv[4][i], xv[5][i]);
        o.w = cvtpk(xv[6][i], xv[7][i]);
        *reinterpret_cast<uint4*>(&Xs[n * 256 + (c0 ^ ((n & 7) * 8))]) = o;
      }
    }
  }
  __syncthreads();

  const int w = tid >> 6, lane = tid & 63, lc = lane & 15, quad = lane >> 4;
  const int swz = (lc & 7) * 8;

  // wave w owns nt = 3w+j, j=0..2  (nt 0..3 = Q, 4..7 = K, 8..11 = V)
  const u16* wsp[3];
  int gsel[3];
#pragma unroll
  for (int j = 0; j < 3; ++j) {
    const int nt = w * 3 + j;
    wsp[j] = (nt < 4) ? wqb : (nt < 8) ? wkb : wvb;
    gsel[j] = nt & 3;
  }

  f32x4 acc[3][4];
#pragma unroll
  for (int j = 0; j < 3; ++j)
#pragma unroll
    for (int ns = 0; ns < 4; ++ns) acc[j][ns] = (f32x4){0.f, 0.f, 0.f, 0.f};

#pragma unroll
  for (int kk = 0; kk < 8; ++kk) {
    short8 bf[3], af[4];
#pragma unroll
    for (int j = 0; j < 3; ++j)
      bf[j] = ld8(wsp[j] + (size_t)(gsel[j] * 16 + lc) * CC + kk * 32 + quad * 8);
#pragma unroll
    for (int ns = 0; ns < 4; ++ns)
      af[ns] = ld8(&Xs[(ns * 16 + lc) * 256 + ((kk * 32 + quad * 8) ^ swz)]);
#pragma unroll
    for (int j = 0; j < 3; ++j)
#pragma unroll
      for (int ns = 0; ns < 4; ++ns)
        acc[j][ns] = __builtin_amdgcn_mfma_f32_16x16x32_bf16(af[ns], bf[j], acc[j][ns], 0, 0, 0);
  }
  // lane holds D[n = ns*16 + quad*4 + r][ch = gsel*16 + lc]

  // pos (Q/K only), vectorized float4
  f32x4 posv[3][4];
#pragma unroll
  for (int j = 0; j < 3; ++j) {
    const int nt = w * 3 + j;
    if (nt < 8) {
#pragma unroll
      for (int ns = 0; ns < 4; ++ns)
        posv[j][ns] = *reinterpret_cast<const f32x4*>(
            pos_e + (size_t)(gsel[j] * 16 + lc) * NN + n0 + ns * 16 + quad * 4);
    }
  }

  __syncthreads();           // all Xs fragment reads complete
  u16* Vst = Xs;             // reuse: Vst[ch][n], swizzled, 8 KiB

#pragma unroll
  for (int j = 0; j < 3; ++j) {
    const int nt = w * 3 + j;
    const int ch = gsel[j] * 16 + lc;
    const float bias = (nt < 4) ? bq[ch] : (nt < 8) ? bk[ch] : bv[ch];
#pragma unroll
    for (int ns = 0; ns < 4; ++ns) {
      if (nt < 8) {
        u16* dst = (nt < 4) ? Qb : Kb;
#pragma unroll
        for (int r = 0; r < 4; ++r) {
          const int n = n0 + ns * 16 + quad * 4 + r;
          float v = acc[j][ns][r] + bias;
          v += posv[j][ns][r];
          if (nt < 4) v *= 0.125f;   // fold 1/(TEMP*sqrt(64)) into Q
          dst[((size_t)(b * NN + n)) * DD + ch] = f2bf(v);
        }
      } else {
        uint2 o2;    // pack 4 consecutive n -> [ch][n] row staging
        o2.x = cvtpk(acc[j][ns][0] + bias, acc[j][ns][1] + bias);
        o2.y = cvtpk(acc[j][ns][2] + bias, acc[j][ns][3] + bias);
        *reinterpret_cast<uint2*>(
            &Vst[ch * 64 + ((ns * 16 + quad * 4) ^ ((ch & 7) * 8))]) = o2;
      }
    }
  }
  __syncthreads();

  // cooperative coalesced V write: row ch = 128B contiguous in n
  {
    const int ch = tid >> 2, part = tid & 3;
    const int sw = (ch & 7) * 8;
    const uint4 a  = *reinterpret_cast<const uint4*>(&Vst[ch * 64 + ((part * 16) ^ sw)]);
    const uint4 c2 = *reinterpret_cast<const uint4*>(&Vst[ch * 64 + ((part * 16 + 8) ^ sw)]);
    u16* dst = Vt + ((size_t)(b * DD + ch)) * NN + n0 + part * 16;
    *reinterpret_cast<uint4*>(dst) = a;
    *reinterpret_cast<uint4*>(dst + 8) = c2;
  }
}

// ============================================================================
// Kernel B: flash attention + fused out-projection.
// Restructured: 128 q-rows / 512 threads / 8 waves per block.
//  - LDS 48 KiB (was 46.1): exactly 2 blocks/CU = 16 waves/CU (was 12), grid
//    512 = 2/CU exactly -> no tail round. Staging instrs per MFMA halved.
//  - TSTR pad replaced by XOR swizzle (16B slot ^= row&7): min-phase b128.
//  - P^T / att pack via v_cvt_pk_bf16_f32 (1 instr/pair, was ~10 VALU ops).
//  - FIXED-max softmax + double-buffered K/V, one barrier/tile (unchanged).
// ============================================================================
#define QB 128

__global__ __launch_bounds__(512, 4) void flash_kernel(
    const u16* __restrict__ Qg, const u16* __restrict__ Kg,
    const u16* __restrict__ Vtg,
    const u16* __restrict__ wob, const float* __restrict__ bo,
    const float* __restrict__ gam, const float* __restrict__ xg,
    float* __restrict__ outg)
{
  const int qt = blockIdx.x, b = blockIdx.y, tid = threadIdx.x;
  const int w = tid >> 6, lane = tid & 63, lc = lane & 15, quad = lane >> 4;
  const int swz = (lc & 7) * 8;
  __shared__ u16 Ks[2][64 * 64];    // [key][d]   swizzled, 16 KiB
  __shared__ u16 Vs[2][64 * 64];    // [d][key]   swizzled, 16 KiB
  __shared__ u16 Ps[8][16 * 64];    // per-wave P^T [q][key]; reused as AttS[128][64]

  const u16* Kbase = Kg + (size_t)b * NN * DD;
  const u16* Vbase = Vtg + (size_t)b * DD * NN;

  // staging geometry: each thread covers one (row, 16B seg) of the 8 KiB tile
  const int r = tid >> 3, seg = (tid & 7) * 8;
  const int sdst = r * 64 + (seg ^ ((r & 7) * 8));
  const u16* kp = Kbase + (size_t)r * DD + seg;
  const u16* vp = Vbase + (size_t)r * NN + seg;

  // Q fragments (held all loop)
  const int qrow = qt * QB + w * 16 + lc;
  short8 qf[2];
#pragma unroll
  for (int kk = 0; kk < 2; ++kk)
    qf[kk] = ld8(Qg + ((size_t)(b * NN + qrow)) * DD + kk * 32 + quad * 8);

  // prefetch + stage tile 0
  uint4 kr = *reinterpret_cast<const uint4*>(kp);
  uint4 vr = *reinterpret_cast<const uint4*>(vp);
  *reinterpret_cast<uint4*>(&Ks[0][sdst]) = kr;
  *reinterpret_cast<uint4*>(&Vs[0][sdst]) = vr;
  __syncthreads();

  f32x4 O[4];
#pragma unroll
  for (int i = 0; i < 4; ++i) O[i] = (f32x4){0.f, 0.f, 0.f, 0.f};
  float lsum = 0.f;

  for (int kt = 0; kt < 64; ++kt) {
    const int cur = kt & 1;
    // issue next tile's global loads (latency overlaps compute below)
    if (kt < 63) {
      kr = *reinterpret_cast<const uint4*>(kp + (size_t)(kt + 1) * (64 * DD));
      vr = *reinterpret_cast<const uint4*>(vp + (kt + 1) * 64);
    }

    // S^T tile: lane holds S^T[key = mf*16+quad*4+r][qcol = lc]
    f32x4 S[4];
#pragma unroll
    for (int mf = 0; mf < 4; ++mf) {
      S[mf] = (f32x4){0.f, 0.f, 0.f, 0.f};
#pragma unroll
      for (int kk = 0; kk < 2; ++kk) {
        short8 af = ld8(&Ks[cur][(mf * 16 + lc) * 64 + ((kk * 32 + quad * 8) ^ swz)]);
        S[mf] = __builtin_amdgcn_mfma_f32_16x16x32_bf16(af, qf[kk], S[mf], 0, 0, 0);
      }
    }

    // fixed-max softmax: p = exp(s), per-lane denominator
    float p[16];
#pragma unroll
    for (int mf = 0; mf < 4; ++mf)
#pragma unroll
      for (int i = 0; i < 4; ++i) {
        float e = __expf(fminf(S[mf][i], 80.f));
        p[mf * 4 + i] = e;
        lsum += e;
      }

    // P^T: C-layout -> B-layout via per-wave LDS (cvt_pk = 1 instr/pair)
#pragma unroll
    for (int mf = 0; mf < 4; ++mf) {
      uint2 pkk;
      pkk.x = cvtpk(p[mf * 4 + 0], p[mf * 4 + 1]);
      pkk.y = cvtpk(p[mf * 4 + 2], p[mf * 4 + 3]);
      *reinterpret_cast<uint2*>(&Ps[w][lc * 64 + ((mf * 16 + quad * 4) ^ swz)]) = pkk;
    }
    short8 pf[2];
#pragma unroll
    for (int kk = 0; kk < 2; ++kk)
      pf[kk] = ld8(&Ps[w][lc * 64 + ((kk * 32 + quad * 8) ^ swz)]);

    // O^T += V^T · P^T
#pragma unroll
    for (int dmf = 0; dmf < 4; ++dmf)
#pragma unroll
      for (int kk = 0; kk < 2; ++kk) {
        short8 vf = ld8(&Vs[cur][(dmf * 16 + lc) * 64 + ((kk * 32 + quad * 8) ^ swz)]);
        O[dmf] = __builtin_amdgcn_mfma_f32_16x16x32_bf16(vf, pf[kk], O[dmf], 0, 0, 0);
      }

    // stage next tile; ONE barrier per tile
    if (kt < 63) {
      const int nxt = cur ^ 1;
      *reinterpret_cast<uint4*>(&Ks[nxt][sdst]) = kr;
      *reinterpret_cast<uint4*>(&Vs[nxt][sdst]) = vr;
      __syncthreads();
    }
  }

  // denominator: reduce per-lane partials across the 4 quads of each q-col
  lsum += __shfl_xor(lsum, 16);
  lsum += __shfl_xor(lsum, 32);
  const float rl = 1.0f / lsum;

  // normalized attended values -> LDS (wave-local region of Ps)
  u16* AttS = &Ps[0][0];   // AttS[n_local][d], n_local = w*16 + lc
#pragma unroll
  for (int mf = 0; mf < 4; ++mf) {
    uint2 o2;
    o2.x = cvtpk(O[mf][0] * rl, O[mf][1] * rl);
    o2.y = cvtpk(O[mf][2] * rl, O[mf][3] * rl);
    *reinterpret_cast<uint2*>(
        &AttS[(w * 16 + lc) * 64 + ((mf * 16 + quad * 4) ^ swz)]) = o2;
  }
  __syncthreads();

  // fused out-projection: out = gamma*(wo·att + bo) + x
  // wave w owns output channels [w*32, w*32+32), all 128 n of the block
  f32x4 acc[2][8];
#pragma unroll
  for (int i = 0; i < 2; ++i)
#pragma unroll
    for (int j = 0; j < 8; ++j) acc[i][j] = (f32x4){0.f, 0.f, 0.f, 0.f};

#pragma unroll
  for (int kk = 0; kk < 2; ++kk) {
    short8 bfr[8];
#pragma unroll
    for (int nt = 0; nt < 8; ++nt)
      bfr[nt] = ld8(&AttS[(nt * 16 + lc) * 64 + ((kk * 32 + quad * 8) ^ swz)]);
#pragma unroll
    for (int mti = 0; mti < 2; ++mti) {
      short8 af = ld8(wob + (size_t)(w * 32 + mti * 16 + lc) * DD + kk * 32 + quad * 8);
#pragma unroll
      for (int nt = 0; nt < 8; ++nt)
        acc[mti][nt] = __builtin_amdgcn_mfma_f32_16x16x32_bf16(af, bfr[nt], acc[mti][nt], 0, 0, 0);
    }
  }

  const float g = gam[0];
  const int n0 = qt * QB;
#pragma unroll
  for (int mti = 0; mti < 2; ++mti)
#pragma unroll
    for (int rr = 0; rr < 4; ++rr) {
      const int co = w * 32 + mti * 16 + quad * 4 + rr;
      const float bov = bo[co];
#pragma unroll
      for (int nt = 0; nt < 8; ++nt) {
        const int n = n0 + nt * 16 + lc;
        const size_t idx = ((size_t)(b * CC + co)) * NN + n;
        outg[idx] = g * (acc[mti][nt][rr] + bov) + xg[idx];
      }
    }
}

// ============================================================================
extern "C" void kernel_launch(void* const* d_in, const int* in_sizes, int n_in,
                              void* d_out, int out_size, void* d_ws, size_t ws_size,
                              hipStream_t stream) {
  const float* x   = (const float*)d_in[0];
  const float* pos = (const float*)d_in[1];
  const float* wq  = (const float*)d_in[2];
  const float* bq  = (const float*)d_in[3];
  const float* wk  = (const float*)d_in[4];
  const float* bk  = (const float*)d_in[5];
  const float* wv  = (const float*)d_in[6];
  const float* bv  = (const float*)d_in[7];
  const float* wo  = (const float*)d_in[8];
  const float* bo  = (const float*)d_in[9];
  const float* gm  = (const float*)d_in[10];
  float* out = (float*)d_out;

  // workspace: Q | K | Vt (each B*N*64 bf16 = 8 MiB) + 4x16384 bf16 weights
  u16* Qb  = (u16*)d_ws;
  u16* Kb  = Qb + (size_t)BB * NN * DD;
  u16* Vt  = Kb + (size_t)BB * NN * DD;
  u16* wqb = Vt + (size_t)BB * NN * DD;
  u16* wkb = wqb + 16384;
  u16* wvb = wkb + 16384;
  u16* wob = wvb + 16384;

  dim3 blk(256);
  prep_kernel<<<dim3(64), blk, 0, stream>>>(wq, wk, wv, wo, wqb, wkb, wvb, wob);
  qkv_kernel<<<dim3(64, 16), blk, 0, stream>>>(x, pos, wqb, wkb, wvb, bq, bk, bv, Qb, Kb, Vt);
  flash_kernel<<<dim3(32, 16), dim3(512), 0, stream>>>(Qb, Kb, Vt, wob, bo, gm, x, out);
}

// Round 2
// 249.805 us; speedup vs baseline: 1.2600x; 1.0015x over previous
//
#include <hip/hip_runtime.h>

typedef unsigned short u16;
typedef unsigned int u32;
typedef __attribute__((ext_vector_type(8))) short short8;
typedef __attribute__((ext_vector_type(4))) float f32x4;
typedef __attribute__((ext_vector_type(16))) float f32x16;

#define DEV static __device__ __forceinline__

// ---- bf16 helpers ----
DEV u16 f2bf(float f) {               // RNE, manual (for scalar stores)
  u32 u = __builtin_bit_cast(u32, f);
  u += 0x7FFFu + ((u >> 16) & 1u);
  return (u16)(u >> 16);
}
DEV u32 cvtpk(float a, float b) {     // {lo=bf16(a), hi=bf16(b)}, HW RNE, 1 instr
  u32 d;
  asm("v_cvt_pk_bf16_f32 %0, %1, %2" : "=v"(d) : "v"(a), "v"(b));
  return d;
}
DEV short8 ld8(const u16* p) {        // 16B bf16 fragment load (global or LDS)
  uint4 v = *reinterpret_cast<const uint4*>(p);
  return __builtin_bit_cast(short8, v);
}

// Build a 32x32x16 B-operand fragment from 8 per-lane f32 values laid out in
// the 32x32 C/D register order (rows (r&3)+8*(r>>2)+4*hi, col = lane&31).
// cvt_pk pairs + permlane32_swap (swaps a_hi <-> b_lo) deliver, per lane,
// 8 consecutive k-values: k = (lane>>5)*8 + j.  [T12 recipe]
DEV short8 frag8(const float* p) {
  u32 a0 = cvtpk(p[0], p[1]);
  u32 a1 = cvtpk(p[2], p[3]);
  u32 b0 = cvtpk(p[4], p[5]);
  u32 b1 = cvtpk(p[6], p[7]);
  asm("v_permlane32_swap_b32 %0, %1" : "+v"(a0), "+v"(b0));
  asm("v_permlane32_swap_b32 %0, %1" : "+v"(a1), "+v"(b1));
  uint4 u;
  u.x = a0; u.y = a1; u.z = b0; u.w = b1;
  return __builtin_bit_cast(short8, u);
}

// Problem constants
#define BB 16
#define CC 256
#define DD 64
#define NN 4096

// ============================================================================
// Kernel P: one-time f32 -> bf16 weight conversion (unchanged).
// ============================================================================
__global__ __launch_bounds__(256) void prep_kernel(
    const float* __restrict__ wq, const float* __restrict__ wk,
    const float* __restrict__ wv, const float* __restrict__ wo,
    u16* __restrict__ wqb, u16* __restrict__ wkb,
    u16* __restrict__ wvb, u16* __restrict__ wob)
{
  int i = blockIdx.x * 256 + threadIdx.x;   // 64 blocks x 256 = 16384
  wqb[i] = f2bf(wq[i]);
  wkb[i] = f2bf(wk[i]);
  wvb[i] = f2bf(wv[i]);
  wob[i] = f2bf(wo[i]);
}

// ============================================================================
// Kernel A: QKV projection (UNCHANGED from round 1 — kept identical so the
// flash rewrite's delta is isolated and qkv surfaces in the next profile).
// ============================================================================
__global__ __launch_bounds__(256, 4) void qkv_kernel(
    const float* __restrict__ xg, const float* __restrict__ pos_e,
    const u16* __restrict__ wqb, const u16* __restrict__ wkb,
    const u16* __restrict__ wvb,
    const float* __restrict__ bq, const float* __restrict__ bk,
    const float* __restrict__ bv,
    u16* __restrict__ Qb, u16* __restrict__ Kb, u16* __restrict__ Vt)
{
  const int nc = blockIdx.x, b = blockIdx.y, tid = threadIdx.x;
  const int n0 = nc * 64;
  __shared__ u16 Xs[64 * 256];   // [n][c] bf16, swizzled; 32 KiB

  {
    const int ng = tid & 15;
    const int ch0 = tid >> 4;
#pragma unroll
    for (int it = 0; it < 2; ++it) {
      const int c0 = (ch0 + 16 * it) * 8;
      f32x4 xv[8];
#pragma unroll
      for (int j = 0; j < 8; ++j)
        xv[j] = *reinterpret_cast<const f32x4*>(
            xg + ((size_t)(b * CC + c0 + j)) * NN + n0 + ng * 4);
#pragma unroll
      for (int i = 0; i < 4; ++i) {
        const int n = ng * 4 + i;
        uint4 o;
        o.x = cvtpk(xv[0][i], xv[1][i]);
        o.y = cvtpk(xv[2][i], xv[3][i]);
        o.z = cvtpk(xv[4][i], xv[5][i]);
        o.w = cvtpk(xv[6][i], xv[7][i]);
        *reinterpret_cast<uint4*>(&Xs[n * 256 + (c0 ^ ((n & 7) * 8))]) = o;
      }
    }
  }
  __syncthreads();

  const int w = tid >> 6, lane = tid & 63, lc = lane & 15, quad = lane >> 4;
  const int swz = (lc & 7) * 8;

  const u16* wsp[3];
  int gsel[3];
#pragma unroll
  for (int j = 0; j < 3; ++j) {
    const int nt = w * 3 + j;
    wsp[j] = (nt < 4) ? wqb : (nt < 8) ? wkb : wvb;
    gsel[j] = nt & 3;
  }

  f32x4 acc[3][4];
#pragma unroll
  for (int j = 0; j < 3; ++j)
#pragma unroll
    for (int ns = 0; ns < 4; ++ns) acc[j][ns] = (f32x4){0.f, 0.f, 0.f, 0.f};

#pragma unroll
  for (int kk = 0; kk < 8; ++kk) {
    short8 bf[3], af[4];
#pragma unroll
    for (int j = 0; j < 3; ++j)
      bf[j] = ld8(wsp[j] + (size_t)(gsel[j] * 16 + lc) * CC + kk * 32 + quad * 8);
#pragma unroll
    for (int ns = 0; ns < 4; ++ns)
      af[ns] = ld8(&Xs[(ns * 16 + lc) * 256 + ((kk * 32 + quad * 8) ^ swz)]);
#pragma unroll
    for (int j = 0; j < 3; ++j)
#pragma unroll
      for (int ns = 0; ns < 4; ++ns)
        acc[j][ns] = __builtin_amdgcn_mfma_f32_16x16x32_bf16(af[ns], bf[j], acc[j][ns], 0, 0, 0);
  }

  f32x4 posv[3][4];
#pragma unroll
  for (int j = 0; j < 3; ++j) {
    const int nt = w * 3 + j;
    if (nt < 8) {
#pragma unroll
      for (int ns = 0; ns < 4; ++ns)
        posv[j][ns] = *reinterpret_cast<const f32x4*>(
            pos_e + (size_t)(gsel[j] * 16 + lc) * NN + n0 + ns * 16 + quad * 4);
    }
  }

  __syncthreads();
  u16* Vst = Xs;

#pragma unroll
  for (int j = 0; j < 3; ++j) {
    const int nt = w * 3 + j;
    const int ch = gsel[j] * 16 + lc;
    const float bias = (nt < 4) ? bq[ch] : (nt < 8) ? bk[ch] : bv[ch];
#pragma unroll
    for (int ns = 0; ns < 4; ++ns) {
      if (nt < 8) {
        u16* dst = (nt < 4) ? Qb : Kb;
#pragma unroll
        for (int r = 0; r < 4; ++r) {
          const int n = n0 + ns * 16 + quad * 4 + r;
          float v = acc[j][ns][r] + bias;
          v += posv[j][ns][r];
          if (nt < 4) v *= 0.125f;
          dst[((size_t)(b * NN + n)) * DD + ch] = f2bf(v);
        }
      } else {
        uint2 o2;
        o2.x = cvtpk(acc[j][ns][0] + bias, acc[j][ns][1] + bias);
        o2.y = cvtpk(acc[j][ns][2] + bias, acc[j][ns][3] + bias);
        *reinterpret_cast<uint2*>(
            &Vst[ch * 64 + ((ns * 16 + quad * 4) ^ ((ch & 7) * 8))]) = o2;
      }
    }
  }
  __syncthreads();

  {
    const int ch = tid >> 2, part = tid & 3;
    const int sw = (ch & 7) * 8;
    const uint4 a  = *reinterpret_cast<const uint4*>(&Vst[ch * 64 + ((part * 16) ^ sw)]);
    const uint4 c2 = *reinterpret_cast<const uint4*>(&Vst[ch * 64 + ((part * 16 + 8) ^ sw)]);
    u16* dst = Vt + ((size_t)(b * DD + ch)) * NN + n0 + part * 16;
    *reinterpret_cast<uint4*>(dst) = a;
    *reinterpret_cast<uint4*>(dst + 8) = c2;
  }
}

// ============================================================================
// Kernel B: flash attention + fused out-projection, 32x32x16 MFMA structure.
//   - 8 waves x (32 q-cols x 32 keys): waves 0-3 take keys 0-31 of each tile,
//     waves 4-7 keys 32-63; partial O/lsum reduced once at the end through
//     the retired Ks/Vs LDS.
//   - P NEVER touches LDS: S^T's 32x32 C-layout -> PV B-fragment via
//     cvt_pk_bf16 pairs + v_permlane32_swap (pure VALU, off the LDS pipe and
//     off the ds_write->lgkmcnt->ds_read critical chain).
//   - Per wave per tile: 8 MFMA (32x32x16), 8 LDS b128 reads (was 16 MFMA /
//     18 reads at 16x16). s_setprio(1) wraps both MFMA clusters (T5).
//   - Fixed-max softmax, double-buffered K/V staging, one barrier/tile, and
//     the 16x16 out-projection epilogue are unchanged from round 1.
// ============================================================================
#define QB 128

__global__ __launch_bounds__(512, 4) void flash_kernel(
    const u16* __restrict__ Qg, const u16* __restrict__ Kg,
    const u16* __restrict__ Vtg,
    const u16* __restrict__ wob, const float* __restrict__ bo,
    const float* __restrict__ gam, const float* __restrict__ xg,
    float* __restrict__ outg)
{
  const int qt = blockIdx.x, b = blockIdx.y, tid = threadIdx.x;
  const int w = tid >> 6, lane = tid & 63;
  const int l31 = lane & 31, hi8 = (lane >> 5) * 8;
  const int swz = (l31 & 7) * 8;
  const int khalf = w >> 2;          // 0: keys 0-31 of tile, 1: keys 32-63
  const int qg = w & 3;              // q-group: rows qg*32 .. qg*32+31

  // pool: Ks[2][4096] | Vs[2][4096] | AttS[8192] | Lred[512]  (u16 units)
  // f32 alias: Ored = poolF[0..8191] (over Ks+Vs), Lred = poolF[12288..12543]
  __shared__ u16 pool[25088];        // 50176 B -> 2 blocks/CU
  u16* const KsA = pool;
  u16* const VsA = pool + 8192;
  u16* const AttS = pool + 16384;
  float* const poolF = reinterpret_cast<float*>(pool);

  const u16* Kbase = Kg + (size_t)b * NN * DD;
  const u16* Vbase = Vtg + (size_t)b * DD * NN;

  // staging geometry: thread covers one (row, 16B seg) of each 8 KiB tile
  const int sr = tid >> 3, seg = (tid & 7) * 8;
  const int sdst = sr * 64 + (seg ^ ((sr & 7) * 8));
  const u16* kp = Kbase + (size_t)sr * DD + seg;
  const u16* vp = Vbase + (size_t)sr * NN + seg;

  // Q fragments (B-operand: col = q = lane&31, k = d = kk*16 + hi8 + j)
  const int qrow = qt * QB + qg * 32 + l31;
  short8 qf[4];
#pragma unroll
  for (int kk = 0; kk < 4; ++kk)
    qf[kk] = ld8(Qg + ((size_t)(b * NN + qrow)) * DD + kk * 16 + hi8);

  // prefetch + stage tile 0
  uint4 kr = *reinterpret_cast<const uint4*>(kp);
  uint4 vr = *reinterpret_cast<const uint4*>(vp);
  *reinterpret_cast<uint4*>(&KsA[sdst]) = kr;
  *reinterpret_cast<uint4*>(&VsA[sdst]) = vr;
  __syncthreads();

  f32x16 O0 = (f32x16)0.0f;          // d rows 0-31  (C-layout), col = q
  f32x16 O1 = (f32x16)0.0f;          // d rows 32-63
  float lsum = 0.f;

  for (int kt = 0; kt < 64; ++kt) {
    const int cur = kt & 1;
    if (kt < 63) {   // issue next tile's global loads early
      kr = *reinterpret_cast<const uint4*>(kp + (size_t)(kt + 1) * (64 * DD));
      vr = *reinterpret_cast<const uint4*>(vp + (kt + 1) * 64);
    }
    const u16* Kc = KsA + cur * 4096;
    const u16* Vc = VsA + cur * 4096;

    // S^T = K · Q^T : C rows = key, cols = q
    f32x16 S = (f32x16)0.0f;
    __builtin_amdgcn_s_setprio(1);
#pragma unroll
    for (int kk = 0; kk < 4; ++kk) {
      short8 af = ld8(&Kc[(khalf * 32 + l31) * 64 + ((kk * 16 + hi8) ^ swz)]);
      S = __builtin_amdgcn_mfma_f32_32x32x16_bf16(af, qf[kk], S, 0, 0, 0);
    }
    __builtin_amdgcn_s_setprio(0);

    // fixed-max softmax: p = exp(s), per-lane denominator (col q is lane-local)
    float p[16];
#pragma unroll
    for (int r = 0; r < 16; ++r) {
      float e = __expf(fminf(S[r], 80.f));
      p[r] = e;
      lsum += e;
    }

    // P -> PV B-fragments fully in-register (cvt_pk + permlane32_swap)
    short8 pf0 = frag8(&p[0]);    // tile-local keys khalf*32 + 0..15
    short8 pf1 = frag8(&p[8]);    // tile-local keys khalf*32 + 16..31

    // O^T += V^T · P^T
    __builtin_amdgcn_s_setprio(1);
#pragma unroll
    for (int kf = 0; kf < 2; ++kf) {
      const short8 pfv = kf ? pf1 : pf0;
      const int ko = (khalf * 32 + kf * 16 + hi8) ^ swz;
      short8 v0 = ld8(&Vc[l31 * 64 + ko]);
      O0 = __builtin_amdgcn_mfma_f32_32x32x16_bf16(v0, pfv, O0, 0, 0, 0);
      short8 v1 = ld8(&Vc[(32 + l31) * 64 + ko]);
      O1 = __builtin_amdgcn_mfma_f32_32x32x16_bf16(v1, pfv, O1, 0, 0, 0);
    }
    __builtin_amdgcn_s_setprio(0);

    if (kt < 63) {   // stage next tile; ONE barrier per tile
      const int nxt = cur ^ 1;
      *reinterpret_cast<uint4*>(&KsA[nxt * 4096 + sdst]) = kr;
      *reinterpret_cast<uint4*>(&VsA[nxt * 4096 + sdst]) = vr;
      __syncthreads();
    }
  }

  __syncthreads();   // drain all Ks/Vs reads before aliasing as Ored

  // per-wave denominator: lane and lane^32 share col q
  lsum += __shfl_xor(lsum, 32);

  // cross-key-half reduction through retired Ks/Vs LDS (f32, XOR-swizzled)
  if (w >= 4) {
    const int base = ((w - 4) * 64 + lane) * 32;
#pragma unroll
    for (int i = 0; i < 4; ++i) {
      f32x4 t0 = {O0[i * 4 + 0], O0[i * 4 + 1], O0[i * 4 + 2], O0[i * 4 + 3]};
      *reinterpret_cast<f32x4*>(&poolF[base + ((i * 4) ^ ((lane & 7) * 4))]) = t0;
      f32x4 t1 = {O1[i * 4 + 0], O1[i * 4 + 1], O1[i * 4 + 2], O1[i * 4 + 3]};
      *reinterpret_cast<f32x4*>(&poolF[base + ((16 + i * 4) ^ ((lane & 7) * 4))]) = t1;
    }
    poolF[12288 + (w - 4) * 64 + lane] = lsum;
  }
  __syncthreads();

  if (w < 4) {
    const int base = (w * 64 + lane) * 32;
#pragma unroll
    for (int i = 0; i < 4; ++i) {
      f32x4 t0 = *reinterpret_cast<const f32x4*>(&poolF[base + ((i * 4) ^ ((lane & 7) * 4))]);
      f32x4 t1 = *reinterpret_cast<const f32x4*>(&poolF[base + ((16 + i * 4) ^ ((lane & 7) * 4))]);
#pragma unroll
      for (int j = 0; j < 4; ++j) {
        O0[i * 4 + j] += t0[j];
        O1[i * 4 + j] += t1[j];
      }
    }
    lsum += poolF[12288 + w * 64 + lane];
    const float rl = 1.0f / lsum;

    // normalized attended values -> AttS[n_local][d] via the same frag trick
    const int nl = w * 32 + l31;      // nl&7 == l31&7 == swz row bits
    float a[16];
#pragma unroll
    for (int r = 0; r < 16; ++r) a[r] = O0[r] * rl;
    short8 f0 = frag8(&a[0]);         // d = 0..7 / 8..15   (by lane half)
    short8 f1 = frag8(&a[8]);         // d = 16..23 / 24..31
    *reinterpret_cast<uint4*>(&AttS[nl * 64 + ((0 + hi8) ^ swz)]) =
        __builtin_bit_cast(uint4, f0);
    *reinterpret_cast<uint4*>(&AttS[nl * 64 + ((16 + hi8) ^ swz)]) =
        __builtin_bit_cast(uint4, f1);
#pragma unroll
    for (int r = 0; r < 16; ++r) a[r] = O1[r] * rl;
    f0 = frag8(&a[0]);
    f1 = frag8(&a[8]);
    *reinterpret_cast<uint4*>(&AttS[nl * 64 + ((32 + hi8) ^ swz)]) =
        __builtin_bit_cast(uint4, f0);
    *reinterpret_cast<uint4*>(&AttS[nl * 64 + ((48 + hi8) ^ swz)]) =
        __builtin_bit_cast(uint4, f1);
  }
  __syncthreads();

  // fused out-projection: out = gamma*(wo·att + bo) + x   (16x16 path, as r1)
  const int lc = lane & 15, quad = lane >> 4;
  const int swz16 = (lc & 7) * 8;
  f32x4 acc[2][8];
#pragma unroll
  for (int i = 0; i < 2; ++i)
#pragma unroll
    for (int j = 0; j < 8; ++j) acc[i][j] = (f32x4){0.f, 0.f, 0.f, 0.f};

#pragma unroll
  for (int kk = 0; kk < 2; ++kk) {
    short8 bfr[8];
#pragma unroll
    for (int nt = 0; nt < 8; ++nt)
      bfr[nt] = ld8(&AttS[(nt * 16 + lc) * 64 + ((kk * 32 + quad * 8) ^ swz16)]);
#pragma unroll
    for (int mti = 0; mti < 2; ++mti) {
      short8 af = ld8(wob + (size_t)(w * 32 + mti * 16 + lc) * DD + kk * 32 + quad * 8);
#pragma unroll
      for (int nt = 0; nt < 8; ++nt)
        acc[mti][nt] = __builtin_amdgcn_mfma_f32_16x16x32_bf16(af, bfr[nt], acc[mti][nt], 0, 0, 0);
    }
  }

  const float g = gam[0];
  const int n0 = qt * QB;
#pragma unroll
  for (int mti = 0; mti < 2; ++mti)
#pragma unroll
    for (int rr = 0; rr < 4; ++rr) {
      const int co = w * 32 + mti * 16 + quad * 4 + rr;
      const float bov = bo[co];
#pragma unroll
      for (int nt = 0; nt < 8; ++nt) {
        const int n = n0 + nt * 16 + lc;
        const size_t idx = ((size_t)(b * CC + co)) * NN + n;
        outg[idx] = g * (acc[mti][nt][rr] + bov) + xg[idx];
      }
    }
}

// ============================================================================
extern "C" void kernel_launch(void* const* d_in, const int* in_sizes, int n_in,
                              void* d_out, int out_size, void* d_ws, size_t ws_size,
                              hipStream_t stream) {
  const float* x   = (const float*)d_in[0];
  const float* pos = (const float*)d_in[1];
  const float* wq  = (const float*)d_in[2];
  const float* bq  = (const float*)d_in[3];
  const float* wk  = (const float*)d_in[4];
  const float* bk  = (const float*)d_in[5];
  const float* wv  = (const float*)d_in[6];
  const float* bv  = (const float*)d_in[7];
  const float* wo  = (const float*)d_in[8];
  const float* bo  = (const float*)d_in[9];
  const float* gm  = (const float*)d_in[10];
  float* out = (float*)d_out;

  // workspace: Q | K | Vt (each B*N*64 bf16 = 8 MiB) + 4x16384 bf16 weights
  u16* Qb  = (u16*)d_ws;
  u16* Kb  = Qb + (size_t)BB * NN * DD;
  u16* Vt  = Kb + (size_t)BB * NN * DD;
  u16* wqb = Vt + (size_t)BB * NN * DD;
  u16* wkb = wqb + 16384;
  u16* wvb = wkb + 16384;
  u16* wob = wvb + 16384;

  dim3 blk(256);
  prep_kernel<<<dim3(64), blk, 0, stream>>>(wq, wk, wv, wo, wqb, wkb, wvb, wob);
  qkv_kernel<<<dim3(64, 16), blk, 0, stream>>>(x, pos, wqb, wkb, wvb, bq, bk, bv, Qb, Kb, Vt);
  flash_kernel<<<dim3(32, 16), dim3(512), 0, stream>>>(Qb, Kb, Vt, wob, bo, gm, x, out);
}

// Round 3
// 247.635 us; speedup vs baseline: 1.2710x; 1.0088x over previous
//
#include <hip/hip_runtime.h>

typedef unsigned short u16;
typedef unsigned int u32;
typedef __attribute__((ext_vector_type(8))) short short8;
typedef __attribute__((ext_vector_type(4))) float f32x4;
typedef __attribute__((ext_vector_type(16))) float f32x16;

#define DEV static __device__ __forceinline__

// ---- bf16 helpers ----
DEV u16 f2bf(float f) {               // RNE, manual (for scalar stores)
  u32 u = __builtin_bit_cast(u32, f);
  u += 0x7FFFu + ((u >> 16) & 1u);
  return (u16)(u >> 16);
}
DEV u32 cvtpk(float a, float b) {     // {lo=bf16(a), hi=bf16(b)}, HW RNE, 1 instr
  u32 d;
  asm("v_cvt_pk_bf16_f32 %0, %1, %2" : "=v"(d) : "v"(a), "v"(b));
  return d;
}
DEV short8 ld8(const u16* p) {        // 16B bf16 fragment load (global or LDS)
  uint4 v = *reinterpret_cast<const uint4*>(p);
  return __builtin_bit_cast(short8, v);
}

// Build a 32x32x16 B-operand fragment from 8 per-lane f32 values laid out in
// the 32x32 C/D register order (rows (r&3)+8*(r>>2)+4*hi, col = lane&31).
// cvt_pk pairs + permlane32_swap (swaps a_hi <-> b_lo) deliver, per lane,
// 8 consecutive k-values: k = (lane>>5)*8 + j.  [T12 recipe]
DEV short8 frag8(const float* p) {
  u32 a0 = cvtpk(p[0], p[1]);
  u32 a1 = cvtpk(p[2], p[3]);
  u32 b0 = cvtpk(p[4], p[5]);
  u32 b1 = cvtpk(p[6], p[7]);
  asm("v_permlane32_swap_b32 %0, %1" : "+v"(a0), "+v"(b0));
  asm("v_permlane32_swap_b32 %0, %1" : "+v"(a1), "+v"(b1));
  uint4 u;
  u.x = a0; u.y = a1; u.z = b0; u.w = b1;
  return __builtin_bit_cast(short8, u);
}

// Problem constants
#define BB 16
#define CC 256
#define DD 64
#define NN 4096

// ============================================================================
// Kernel P: one-time f32 -> bf16 weight conversion (unchanged).
// ============================================================================
__global__ __launch_bounds__(256) void prep_kernel(
    const float* __restrict__ wq, const float* __restrict__ wk,
    const float* __restrict__ wv, const float* __restrict__ wo,
    u16* __restrict__ wqb, u16* __restrict__ wkb,
    u16* __restrict__ wvb, u16* __restrict__ wob)
{
  int i = blockIdx.x * 256 + threadIdx.x;   // 64 blocks x 256 = 16384
  wqb[i] = f2bf(wq[i]);
  wkb[i] = f2bf(wk[i]);
  wvb[i] = f2bf(wv[i]);
  wob[i] = f2bf(wo[i]);
}

// ============================================================================
// Kernel A: QKV projection.
// Round-3 changes (epilogue/register-pressure attack; staging + MFMA-loop
// loads unchanged):
//  (1) Q/K tiles use OPERAND-SWAPPED MFMA: D' = W·X^T (A = weight fragment,
//      B = Xs fragment — same loads, swapped call). Lane then holds 4
//      consecutive channels at fixed n -> Q/K epilogue becomes packed uint2
//      stores (4 wave-stores/tile at 32-B segments, was 16 stores of 2-B
//      scatter).
//  (2) posv register array (48 VGPRs live across epilogue) eliminated: pos
//      read scalar at use (L2-resident), bias as one f32x4 per tile.
//  (3) V tiles keep the unswapped layout + LDS transpose + coalesced write.
// Numerics unchanged: (acc+bias)+pos order, exact *0.125f, RNE pack.
// ============================================================================
__global__ __launch_bounds__(256, 4) void qkv_kernel(
    const float* __restrict__ xg, const float* __restrict__ pos_e,
    const u16* __restrict__ wqb, const u16* __restrict__ wkb,
    const u16* __restrict__ wvb,
    const float* __restrict__ bq, const float* __restrict__ bk,
    const float* __restrict__ bv,
    u16* __restrict__ Qb, u16* __restrict__ Kb, u16* __restrict__ Vt)
{
  const int nc = blockIdx.x, b = blockIdx.y, tid = threadIdx.x;
  const int n0 = nc * 64;
  __shared__ u16 Xs[64 * 256];   // [n][c] bf16, swizzled; 32 KiB

  {
    const int ng = tid & 15;
    const int ch0 = tid >> 4;
#pragma unroll
    for (int it = 0; it < 2; ++it) {
      const int c0 = (ch0 + 16 * it) * 8;
      f32x4 xv[8];
#pragma unroll
      for (int j = 0; j < 8; ++j)
        xv[j] = *reinterpret_cast<const f32x4*>(
            xg + ((size_t)(b * CC + c0 + j)) * NN + n0 + ng * 4);
#pragma unroll
      for (int i = 0; i < 4; ++i) {
        const int n = ng * 4 + i;
        uint4 o;
        o.x = cvtpk(xv[0][i], xv[1][i]);
        o.y = cvtpk(xv[2][i], xv[3][i]);
        o.z = cvtpk(xv[4][i], xv[5][i]);
        o.w = cvtpk(xv[6][i], xv[7][i]);
        *reinterpret_cast<uint4*>(&Xs[n * 256 + (c0 ^ ((n & 7) * 8))]) = o;
      }
    }
  }
  __syncthreads();

  const int w = tid >> 6, lane = tid & 63, lc = lane & 15, quad = lane >> 4;
  const int swz = (lc & 7) * 8;

  const u16* wsp[3];
  int gsel[3];
#pragma unroll
  for (int j = 0; j < 3; ++j) {
    const int nt = w * 3 + j;
    wsp[j] = (nt < 4) ? wqb : (nt < 8) ? wkb : wvb;
    gsel[j] = nt & 3;
  }

  f32x4 acc[3][4];
#pragma unroll
  for (int j = 0; j < 3; ++j)
#pragma unroll
    for (int ns = 0; ns < 4; ++ns) acc[j][ns] = (f32x4){0.f, 0.f, 0.f, 0.f};

#pragma unroll
  for (int kk = 0; kk < 8; ++kk) {
    short8 bf[3], af[4];
#pragma unroll
    for (int j = 0; j < 3; ++j)
      bf[j] = ld8(wsp[j] + (size_t)(gsel[j] * 16 + lc) * CC + kk * 32 + quad * 8);
#pragma unroll
    for (int ns = 0; ns < 4; ++ns)
      af[ns] = ld8(&Xs[(ns * 16 + lc) * 256 + ((kk * 32 + quad * 8) ^ swz)]);
#pragma unroll
    for (int j = 0; j < 3; ++j) {
      const int nt = w * 3 + j;
#pragma unroll
      for (int ns = 0; ns < 4; ++ns) {
        if (nt < 8)   // swapped: rows = ch, cols = n
          acc[j][ns] = __builtin_amdgcn_mfma_f32_16x16x32_bf16(bf[j], af[ns], acc[j][ns], 0, 0, 0);
        else          // unswapped: rows = n, cols = ch (feeds V transpose path)
          acc[j][ns] = __builtin_amdgcn_mfma_f32_16x16x32_bf16(af[ns], bf[j], acc[j][ns], 0, 0, 0);
      }
    }
  }

  __syncthreads();
  u16* Vst = Xs;

#pragma unroll
  for (int j = 0; j < 3; ++j) {
    const int nt = w * 3 + j;
    if (nt < 8) {
      // lane holds D[ch = gsel*16 + quad*4 + r][n = n0 + ns*16 + lc]
      u16* dst = (nt < 4) ? Qb : Kb;
      const float* bsrc = (nt < 4) ? bq : bk;
      const int ch0 = gsel[j] * 16 + quad * 4;
      const f32x4 bias4 = *reinterpret_cast<const f32x4*>(bsrc + ch0);
#pragma unroll
      for (int ns = 0; ns < 4; ++ns) {
        const int n = n0 + ns * 16 + lc;
        float v[4];
#pragma unroll
        for (int r = 0; r < 4; ++r) {
          v[r] = acc[j][ns][r] + bias4[r] + pos_e[(size_t)(ch0 + r) * NN + n];
          if (nt < 4) v[r] *= 0.125f;   // fold 1/(TEMP*sqrt(64)) into Q
        }
        uint2 o2;
        o2.x = cvtpk(v[0], v[1]);
        o2.y = cvtpk(v[2], v[3]);
        *reinterpret_cast<uint2*>(&dst[((size_t)(b * NN + n)) * DD + ch0]) = o2;
      }
    } else {
      // lane holds D[n = n0 + ns*16 + quad*4 + r][ch = gsel*16 + lc]
      const int ch = gsel[j] * 16 + lc;
      const float bias = bv[ch];
#pragma unroll
      for (int ns = 0; ns < 4; ++ns) {
        uint2 o2;
        o2.x = cvtpk(acc[j][ns][0] + bias, acc[j][ns][1] + bias);
        o2.y = cvtpk(acc[j][ns][2] + bias, acc[j][ns][3] + bias);
        *reinterpret_cast<uint2*>(
            &Vst[ch * 64 + ((ns * 16 + quad * 4) ^ ((ch & 7) * 8))]) = o2;
      }
    }
  }
  __syncthreads();

  {
    const int ch = tid >> 2, part = tid & 3;
    const int sw = (ch & 7) * 8;
    const uint4 a  = *reinterpret_cast<const uint4*>(&Vst[ch * 64 + ((part * 16) ^ sw)]);
    const uint4 c2 = *reinterpret_cast<const uint4*>(&Vst[ch * 64 + ((part * 16 + 8) ^ sw)]);
    u16* dst = Vt + ((size_t)(b * DD + ch)) * NN + n0 + part * 16;
    *reinterpret_cast<uint4*>(dst) = a;
    *reinterpret_cast<uint4*>(dst + 8) = c2;
  }
}

// ============================================================================
// Kernel B: flash attention + fused out-projection, 32x32x16 MFMA structure.
// UNCHANGED from round 2 (verified; kept byte-identical to isolate the qkv
// delta and keep it as the counter anchor).
// ============================================================================
#define QB 128

__global__ __launch_bounds__(512, 4) void flash_kernel(
    const u16* __restrict__ Qg, const u16* __restrict__ Kg,
    const u16* __restrict__ Vtg,
    const u16* __restrict__ wob, const float* __restrict__ bo,
    const float* __restrict__ gam, const float* __restrict__ xg,
    float* __restrict__ outg)
{
  const int qt = blockIdx.x, b = blockIdx.y, tid = threadIdx.x;
  const int w = tid >> 6, lane = tid & 63;
  const int l31 = lane & 31, hi8 = (lane >> 5) * 8;
  const int swz = (l31 & 7) * 8;
  const int khalf = w >> 2;          // 0: keys 0-31 of tile, 1: keys 32-63
  const int qg = w & 3;              // q-group: rows qg*32 .. qg*32+31

  // pool: Ks[2][4096] | Vs[2][4096] | AttS[8192] | Lred[512]  (u16 units)
  __shared__ u16 pool[25088];        // 50176 B -> 2 blocks/CU
  u16* const KsA = pool;
  u16* const VsA = pool + 8192;
  u16* const AttS = pool + 16384;
  float* const poolF = reinterpret_cast<float*>(pool);

  const u16* Kbase = Kg + (size_t)b * NN * DD;
  const u16* Vbase = Vtg + (size_t)b * DD * NN;

  // staging geometry: thread covers one (row, 16B seg) of each 8 KiB tile
  const int sr = tid >> 3, seg = (tid & 7) * 8;
  const int sdst = sr * 64 + (seg ^ ((sr & 7) * 8));
  const u16* kp = Kbase + (size_t)sr * DD + seg;
  const u16* vp = Vbase + (size_t)sr * NN + seg;

  // Q fragments (B-operand: col = q = lane&31, k = d = kk*16 + hi8 + j)
  const int qrow = qt * QB + qg * 32 + l31;
  short8 qf[4];
#pragma unroll
  for (int kk = 0; kk < 4; ++kk)
    qf[kk] = ld8(Qg + ((size_t)(b * NN + qrow)) * DD + kk * 16 + hi8);

  // prefetch + stage tile 0
  uint4 kr = *reinterpret_cast<const uint4*>(kp);
  uint4 vr = *reinterpret_cast<const uint4*>(vp);
  *reinterpret_cast<uint4*>(&KsA[sdst]) = kr;
  *reinterpret_cast<uint4*>(&VsA[sdst]) = vr;
  __syncthreads();

  f32x16 O0 = (f32x16)0.0f;          // d rows 0-31  (C-layout), col = q
  f32x16 O1 = (f32x16)0.0f;          // d rows 32-63
  float lsum = 0.f;

  for (int kt = 0; kt < 64; ++kt) {
    const int cur = kt & 1;
    if (kt < 63) {   // issue next tile's global loads early
      kr = *reinterpret_cast<const uint4*>(kp + (size_t)(kt + 1) * (64 * DD));
      vr = *reinterpret_cast<const uint4*>(vp + (kt + 1) * 64);
    }
    const u16* Kc = KsA + cur * 4096;
    const u16* Vc = VsA + cur * 4096;

    // S^T = K · Q^T : C rows = key, cols = q
    f32x16 S = (f32x16)0.0f;
    __builtin_amdgcn_s_setprio(1);
#pragma unroll
    for (int kk = 0; kk < 4; ++kk) {
      short8 af = ld8(&Kc[(khalf * 32 + l31) * 64 + ((kk * 16 + hi8) ^ swz)]);
      S = __builtin_amdgcn_mfma_f32_32x32x16_bf16(af, qf[kk], S, 0, 0, 0);
    }
    __builtin_amdgcn_s_setprio(0);

    // fixed-max softmax: p = exp(s), per-lane denominator (col q is lane-local)
    float p[16];
#pragma unroll
    for (int r = 0; r < 16; ++r) {
      float e = __expf(fminf(S[r], 80.f));
      p[r] = e;
      lsum += e;
    }

    // P -> PV B-fragments fully in-register (cvt_pk + permlane32_swap)
    short8 pf0 = frag8(&p[0]);    // tile-local keys khalf*32 + 0..15
    short8 pf1 = frag8(&p[8]);    // tile-local keys khalf*32 + 16..31

    // O^T += V^T · P^T
    __builtin_amdgcn_s_setprio(1);
#pragma unroll
    for (int kf = 0; kf < 2; ++kf) {
      const short8 pfv = kf ? pf1 : pf0;
      const int ko = (khalf * 32 + kf * 16 + hi8) ^ swz;
      short8 v0 = ld8(&Vc[l31 * 64 + ko]);
      O0 = __builtin_amdgcn_mfma_f32_32x32x16_bf16(v0, pfv, O0, 0, 0, 0);
      short8 v1 = ld8(&Vc[(32 + l31) * 64 + ko]);
      O1 = __builtin_amdgcn_mfma_f32_32x32x16_bf16(v1, pfv, O1, 0, 0, 0);
    }
    __builtin_amdgcn_s_setprio(0);

    if (kt < 63) {   // stage next tile; ONE barrier per tile
      const int nxt = cur ^ 1;
      *reinterpret_cast<uint4*>(&KsA[nxt * 4096 + sdst]) = kr;
      *reinterpret_cast<uint4*>(&VsA[nxt * 4096 + sdst]) = vr;
      __syncthreads();
    }
  }

  __syncthreads();   // drain all Ks/Vs reads before aliasing as Ored

  // per-wave denominator: lane and lane^32 share col q
  lsum += __shfl_xor(lsum, 32);

  // cross-key-half reduction through retired Ks/Vs LDS (f32, XOR-swizzled)
  if (w >= 4) {
    const int base = ((w - 4) * 64 + lane) * 32;
#pragma unroll
    for (int i = 0; i < 4; ++i) {
      f32x4 t0 = {O0[i * 4 + 0], O0[i * 4 + 1], O0[i * 4 + 2], O0[i * 4 + 3]};
      *reinterpret_cast<f32x4*>(&poolF[base + ((i * 4) ^ ((lane & 7) * 4))]) = t0;
      f32x4 t1 = {O1[i * 4 + 0], O1[i * 4 + 1], O1[i * 4 + 2], O1[i * 4 + 3]};
      *reinterpret_cast<f32x4*>(&poolF[base + ((16 + i * 4) ^ ((lane & 7) * 4))]) = t1;
    }
    poolF[12288 + (w - 4) * 64 + lane] = lsum;
  }
  __syncthreads();

  if (w < 4) {
    const int base = (w * 64 + lane) * 32;
#pragma unroll
    for (int i = 0; i < 4; ++i) {
      f32x4 t0 = *reinterpret_cast<const f32x4*>(&poolF[base + ((i * 4) ^ ((lane & 7) * 4))]);
      f32x4 t1 = *reinterpret_cast<const f32x4*>(&poolF[base + ((16 + i * 4) ^ ((lane & 7) * 4))]);
#pragma unroll
      for (int j = 0; j < 4; ++j) {
        O0[i * 4 + j] += t0[j];
        O1[i * 4 + j] += t1[j];
      }
    }
    lsum += poolF[12288 + w * 64 + lane];
    const float rl = 1.0f / lsum;

    // normalized attended values -> AttS[n_local][d] via the same frag trick
    const int nl = w * 32 + l31;      // nl&7 == l31&7 == swz row bits
    float a[16];
#pragma unroll
    for (int r = 0; r < 16; ++r) a[r] = O0[r] * rl;
    short8 f0 = frag8(&a[0]);         // d = 0..7 / 8..15   (by lane half)
    short8 f1 = frag8(&a[8]);         // d = 16..23 / 24..31
    *reinterpret_cast<uint4*>(&AttS[nl * 64 + ((0 + hi8) ^ swz)]) =
        __builtin_bit_cast(uint4, f0);
    *reinterpret_cast<uint4*>(&AttS[nl * 64 + ((16 + hi8) ^ swz)]) =
        __builtin_bit_cast(uint4, f1);
#pragma unroll
    for (int r = 0; r < 16; ++r) a[r] = O1[r] * rl;
    f0 = frag8(&a[0]);
    f1 = frag8(&a[8]);
    *reinterpret_cast<uint4*>(&AttS[nl * 64 + ((32 + hi8) ^ swz)]) =
        __builtin_bit_cast(uint4, f0);
    *reinterpret_cast<uint4*>(&AttS[nl * 64 + ((48 + hi8) ^ swz)]) =
        __builtin_bit_cast(uint4, f1);
  }
  __syncthreads();

  // fused out-projection: out = gamma*(wo·att + bo) + x   (16x16 path)
  const int lc = lane & 15, quad = lane >> 4;
  const int swz16 = (lc & 7) * 8;
  f32x4 acc[2][8];
#pragma unroll
  for (int i = 0; i < 2; ++i)
#pragma unroll
    for (int j = 0; j < 8; ++j) acc[i][j] = (f32x4){0.f, 0.f, 0.f, 0.f};

#pragma unroll
  for (int kk = 0; kk < 2; ++kk) {
    short8 bfr[8];
#pragma unroll
    for (int nt = 0; nt < 8; ++nt)
      bfr[nt] = ld8(&AttS[(nt * 16 + lc) * 64 + ((kk * 32 + quad * 8) ^ swz16)]);
#pragma unroll
    for (int mti = 0; mti < 2; ++mti) {
      short8 af = ld8(wob + (size_t)(w * 32 + mti * 16 + lc) * DD + kk * 32 + quad * 8);
#pragma unroll
      for (int nt = 0; nt < 8; ++nt)
        acc[mti][nt] = __builtin_amdgcn_mfma_f32_16x16x32_bf16(af, bfr[nt], acc[mti][nt], 0, 0, 0);
    }
  }

  const float g = gam[0];
  const int n0 = qt * QB;
#pragma unroll
  for (int mti = 0; mti < 2; ++mti)
#pragma unroll
    for (int rr = 0; rr < 4; ++rr) {
      const int co = w * 32 + mti * 16 + quad * 4 + rr;
      const float bov = bo[co];
#pragma unroll
      for (int nt = 0; nt < 8; ++nt) {
        const int n = n0 + nt * 16 + lc;
        const size_t idx = ((size_t)(b * CC + co)) * NN + n;
        outg[idx] = g * (acc[mti][nt][rr] + bov) + xg[idx];
      }
    }
}

// ============================================================================
extern "C" void kernel_launch(void* const* d_in, const int* in_sizes, int n_in,
                              void* d_out, int out_size, void* d_ws, size_t ws_size,
                              hipStream_t stream) {
  const float* x   = (const float*)d_in[0];
  const float* pos = (const float*)d_in[1];
  const float* wq  = (const float*)d_in[2];
  const float* bq  = (const float*)d_in[3];
  const float* wk  = (const float*)d_in[4];
  const float* bk  = (const float*)d_in[5];
  const float* wv  = (const float*)d_in[6];
  const float* bv  = (const float*)d_in[7];
  const float* wo  = (const float*)d_in[8];
  const float* bo  = (const float*)d_in[9];
  const float* gm  = (const float*)d_in[10];
  float* out = (float*)d_out;

  // workspace: Q | K | Vt (each B*N*64 bf16 = 8 MiB) + 4x16384 bf16 weights
  u16* Qb  = (u16*)d_ws;
  u16* Kb  = Qb + (size_t)BB * NN * DD;
  u16* Vt  = Kb + (size_t)BB * NN * DD;
  u16* wqb = Vt + (size_t)BB * NN * DD;
  u16* wkb = wqb + 16384;
  u16* wvb = wkb + 16384;
  u16* wob = wvb + 16384;

  dim3 blk(256);
  prep_kernel<<<dim3(64), blk, 0, stream>>>(wq, wk, wv, wo, wqb, wkb, wvb, wob);
  qkv_kernel<<<dim3(64, 16), blk, 0, stream>>>(x, pos, wqb, wkb, wvb, bq, bk, bv, Qb, Kb, Vt);
  flash_kernel<<<dim3(32, 16), dim3(512), 0, stream>>>(Qb, Kb, Vt, wob, bo, gm, x, out);
}